// Round 13
// baseline (1280.087 us; speedup 1.0000x reference)
//
#include <hip/hip_runtime.h>
#include <cstdint>

#define B_ 64
#define N_ 4096
#define D_ 256
#define NS_ 8
#define HID_ 512
#define TOK_ 64
#define EPS_ 1e-8f
#define SCALE_ 0.0625f
#define LN_EPS_ 1e-5f

typedef _Float16 f16;
typedef __attribute__((ext_vector_type(4))) _Float16 f16x4;
typedef __attribute__((ext_vector_type(8))) _Float16 f16x8;
typedef __attribute__((ext_vector_type(4))) float f32x4;

#define MFMA16(a, b, c) __builtin_amdgcn_mfma_f32_16x16x32_f16(a, b, c, 0, 0, 0)

// ---------------- merged setup: xh LN-cast | WkX | GRU-wT cast | slots | w1/w2 cast ----
__global__ __launch_bounds__(256) void k_setup(
    const float* __restrict__ in, const float* __restrict__ gin,
    const float* __restrict__ bin, f16* __restrict__ xh,
    const float* __restrict__ Wk, float* __restrict__ WkX,
    const float* __restrict__ wi, const float* __restrict__ wh,
    f16* __restrict__ wiTh, f16* __restrict__ whTh,
    const float* __restrict__ noise, const float* __restrict__ mu,
    const float* __restrict__ ls, float* __restrict__ slots,
    const float* __restrict__ w1, const float* __restrict__ w2,
    f16* __restrict__ w1h, f16* __restrict__ w2h) {
  const int blk = blockIdx.x;
  const int t = threadIdx.x;
  if (blk < 65536) {
    // xh = f16(LN(inputs)), wave per row
    const int wave = t >> 6, lane = t & 63;
    const size_t row = (size_t)blk * 4 + wave;
    const float* r = in + row * D_;
    float4 a = *(const float4*)(r + lane * 4);
    float s1 = a.x + a.y + a.z + a.w;
    float s2 = a.x * a.x + a.y * a.y + a.z * a.z + a.w * a.w;
    #pragma unroll
    for (int m = 32; m >= 1; m >>= 1) { s1 += __shfl_xor(s1, m, 64); s2 += __shfl_xor(s2, m, 64); }
    const float mean = s1 * (1.f / D_);
    const float rstd = rsqrtf(s2 * (1.f / D_) - mean * mean + LN_EPS_);
    float4 gg = *(const float4*)(gin + lane * 4);
    float4 bv = *(const float4*)(bin + lane * 4);
    f16x4 o;
    o[0] = (f16)((a.x - mean) * rstd * gg.x + bv.x);
    o[1] = (f16)((a.y - mean) * rstd * gg.y + bv.y);
    o[2] = (f16)((a.z - mean) * rstd * gg.z + bv.z);
    o[3] = (f16)((a.w - mean) * rstd * gg.w + bv.w);
    *(f16x4*)(xh + row * D_ + lane * 4) = o;
  } else if (blk < 65792) {
    const int e = blk - 65536;
    WkX[t * 256 + e] = Wk[e * 256 + t];
  } else if (blk < 66560) {
    const int idx = (blk - 65792) * 256 + t;
    const int o = idx >> 8, d = idx & 255;
    wiTh[d * 768 + o] = (f16)wi[idx];
    whTh[d * 768 + o] = (f16)wh[idx];
  } else if (blk < 67072) {
    const int idx = (blk - 66560) * 256 + t;
    const int d = idx & 255;
    slots[idx] = mu[d] + __expf(ls[d]) * noise[idx];
  } else if (blk < 67584) {
    const int idx = (blk - 67072) * 256 + t;
    w1h[idx] = (f16)w1[idx];
  } else {
    const int idx = (blk - 67584) * 256 + t;
    w2h[idx] = (f16)w2[idx];
  }
}

// ---------------- M[c][e] = SCALE * sum_d Wq[c][d] * WkX[d][e] ----------------
__global__ __launch_bounds__(256) void k_m(const float* __restrict__ Wq,
                                           const float* __restrict__ WkX,
                                           float* __restrict__ M) {
  __shared__ float wq[256];
  const int c = blockIdx.x, e = threadIdx.x;
  wq[e] = Wq[c * 256 + e];
  __syncthreads();
  float a0 = 0.f, a1 = 0.f, a2 = 0.f, a3 = 0.f;
  #pragma unroll 8
  for (int d = 0; d < 256; d += 4) {
    a0 = fmaf(wq[d],     WkX[(d)     * 256 + e], a0);
    a1 = fmaf(wq[d + 1], WkX[(d + 1) * 256 + e], a1);
    a2 = fmaf(wq[d + 2], WkX[(d + 2) * 256 + e], a2);
    a3 = fmaf(wq[d + 3], WkX[(d + 3) * 256 + e], a3);
  }
  M[c * 256 + e] = (a0 + a1 + a2 + a3) * SCALE_;
}

// ---------------- qkh = f16( LN(slots) @ M ) + zero ur/asum (once) ----------------
__global__ __launch_bounds__(256) void k_qk(const float* __restrict__ slots,
    const float* __restrict__ g, const float* __restrict__ b,
    const float* __restrict__ M, f16* __restrict__ qkh,
    float* __restrict__ ur, float* __restrict__ asum) {
  const int row = blockIdx.x;
  const int t = threadIdx.x;
  ur[(size_t)row * D_ + t] = 0.f;
  if (t == 0) asum[row] = 0.f;
  __shared__ float sl[256];
  __shared__ float red1[4], red2[4];
  float val = slots[(size_t)row * D_ + t];
  float s1 = val, s2 = val * val;
  #pragma unroll
  for (int m = 32; m >= 1; m >>= 1) { s1 += __shfl_xor(s1, m, 64); s2 += __shfl_xor(s2, m, 64); }
  int wave = t >> 6, lane = t & 63;
  if (lane == 0) { red1[wave] = s1; red2[wave] = s2; }
  __syncthreads();
  s1 = red1[0] + red1[1] + red1[2] + red1[3];
  s2 = red2[0] + red2[1] + red2[2] + red2[3];
  float mean = s1 * (1.f / D_);
  float rstd = rsqrtf(s2 * (1.f / D_) - mean * mean + LN_EPS_);
  sl[t] = (val - mean) * rstd * g[t] + b[t];
  __syncthreads();
  float a0 = 0.f, a1 = 0.f, a2 = 0.f, a3 = 0.f;
  #pragma unroll 8
  for (int d = 0; d < D_; d += 4) {
    a0 = fmaf(sl[d],     M[(d)     * D_ + t], a0);
    a1 = fmaf(sl[d + 1], M[(d + 1) * D_ + t], a1);
    a2 = fmaf(sl[d + 2], M[(d + 2) * D_ + t], a2);
    a3 = fmaf(sl[d + 3], M[(d + 3) * D_ + t], a3);
  }
  qkh[((size_t)(row >> 3) * 16 + (row & 7)) * D_ + t] = (f16)(a0 + a1 + a2 + a3);
}

// ---------------- MFMA attention: dots + softmax + asum + u_raw (TOK_=64) ----------------
// LDS 43 KB -> 3 blocks/CU. Phase A: wave per 16-token N-tile (MFMA).
// Phase B: wave-per-2-slots from LDS tile, direct global atomics.
__global__ __launch_bounds__(256) void k_attn_upd(
    const f16* __restrict__ xh, const f16* __restrict__ qkh,
    float* __restrict__ ur, float* __restrict__ asum) {
  __shared__ __align__(16) f16 xt[TOK_ * 256];   // 32 KB, chunk-swizzled
  __shared__ __align__(16) f16 qs[16 * 256];     // 8 KB (rows 8-15 pad)
  __shared__ float wv_s[TOK_ * 12];              // 3 KB
  const int b = blockIdx.y;
  const int jt = blockIdx.x * TOK_;
  const int tid = threadIdx.x;
  const int wave = tid >> 6, lane = tid & 63;

  // stage qs
  {
    const int r = tid >> 4, c0 = (tid & 15) * 2;
    const f16* src = qkh + ((size_t)b * 16 + r) * D_;
    *(f16x8*)&qs[r * 256 + ((c0)     ^ (r & 7)) * 8] = *(const f16x8*)(src + c0 * 8);
    *(f16x8*)&qs[r * 256 + ((c0 + 1) ^ (r & 7)) * 8] = *(const f16x8*)(src + c0 * 8 + 8);
  }
  // stage xt: 8 rounds, coalesced loads, swizzled ds_write
  {
    const f16* src = xh + ((size_t)b * N_ + jt) * D_;
    #pragma unroll
    for (int i = 0; i < 8; ++i) {
      const int r = i * 8 + (tid >> 5), c = tid & 31;
      f16x8 v = *(const f16x8*)(src + r * 256 + c * 8);
      *(f16x8*)&xt[r * 256 + (c ^ (r & 7)) * 8] = v;
    }
  }
  __syncthreads();

  // phase A: MFMA dots, one 16-token N-tile per wave
  const int kg = lane >> 4;
  f16x8 afr[8];
  {
    const int arow = lane & 15;
    #pragma unroll
    for (int kk = 0; kk < 8; ++kk)
      afr[kk] = *(const f16x8*)&qs[arow * 256 + ((kk * 4 + kg) ^ (arow & 7)) * 8];
  }
  {
    const int tok = wave * 16 + (lane & 15);
    f32x4 acc = {0.f, 0.f, 0.f, 0.f};
    #pragma unroll
    for (int kk = 0; kk < 8; ++kk) {
      f16x8 bf = *(const f16x8*)&xt[tok * 256 + ((kk * 4 + kg) ^ (tok & 7)) * 8];
      acc = MFMA16(afr[kk], bf, acc);
    }
    float o0 = __shfl_xor(acc[0], 16, 64);
    float o1 = __shfl_xor(acc[1], 16, 64);
    float o2 = __shfl_xor(acc[2], 16, 64);
    float o3 = __shfl_xor(acc[3], 16, 64);
    if (lane < 32) {
      float m = fmaxf(fmaxf(fmaxf(acc[0], acc[1]), fmaxf(acc[2], acc[3])),
                      fmaxf(fmaxf(o0, o1), fmaxf(o2, o3)));
      float e0 = __expf(acc[0] - m), e1 = __expf(acc[1] - m);
      float e2 = __expf(acc[2] - m), e3 = __expf(acc[3] - m);
      float sm = e0 + e1 + e2 + e3;
      float so = __shfl_xor(sm, 16, 64);
      float inv = 1.f / (sm + so);
      float4 wv;
      wv.x = e0 * inv + EPS_; wv.y = e1 * inv + EPS_;
      wv.z = e2 * inv + EPS_; wv.w = e3 * inv + EPS_;
      *(float4*)&wv_s[tok * 12 + (lane >> 4) * 4] = wv;
      float r0 = wv.x, r1 = wv.y, r2 = wv.z, r3 = wv.w;
      #pragma unroll
      for (int mm = 1; mm <= 8; mm <<= 1) {
        r0 += __shfl_xor(r0, mm, 64); r1 += __shfl_xor(r1, mm, 64);
        r2 += __shfl_xor(r2, mm, 64); r3 += __shfl_xor(r3, mm, 64);
      }
      if ((lane & 15) == 0) {
        const int sb = (lane >> 4) * 4;
        atomicAdd(&asum[b * NS_ + sb + 0], r0);
        atomicAdd(&asum[b * NS_ + sb + 1], r1);
        atomicAdd(&asum[b * NS_ + sb + 2], r2);
        atomicAdd(&asum[b * NS_ + sb + 3], r3);
      }
    }
  }
  __syncthreads();

  // phase B: wave -> slots (2w, 2w+1); lane -> d-quad; read LDS tile
  {
    const int i0 = wave * 2;
    const int ch0 = lane >> 1, sub = (lane & 1) * 4;
    float a0[4] = {0.f, 0.f, 0.f, 0.f};
    float a1[4] = {0.f, 0.f, 0.f, 0.f};
    #pragma unroll 4
    for (int j = 0; j < TOK_; ++j) {
      f16x4 v = *(const f16x4*)&xt[j * 256 + (ch0 ^ (j & 7)) * 8 + sub];
      float vx = (float)v[0], vy = (float)v[1], vz = (float)v[2], vw = (float)v[3];
      float w0 = wv_s[j * 12 + i0];
      float w1 = wv_s[j * 12 + i0 + 1];
      a0[0] = fmaf(w0, vx, a0[0]); a0[1] = fmaf(w0, vy, a0[1]);
      a0[2] = fmaf(w0, vz, a0[2]); a0[3] = fmaf(w0, vw, a0[3]);
      a1[0] = fmaf(w1, vx, a1[0]); a1[1] = fmaf(w1, vy, a1[1]);
      a1[2] = fmaf(w1, vz, a1[2]); a1[3] = fmaf(w1, vw, a1[3]);
    }
    float* u0 = ur + ((size_t)b * NS_ + i0) * D_ + lane * 4;
    float* u1 = u0 + D_;
    #pragma unroll
    for (int c = 0; c < 4; ++c) { atomicAdd(u0 + c, a0[c]); atomicAdd(u1 + c, a1[c]); }
  }
}

// ---------------- GRU + LN + MLP + next-qk, TWO rows per block, f16 weights ----------------
__global__ __launch_bounds__(256) void k_gru_mlp(
    float* __restrict__ ur, float* __restrict__ asum,
    const float* __restrict__ slots, const float* __restrict__ Wv,
    const f16* __restrict__ wiTh, const f16* __restrict__ whTh,
    const float* __restrict__ bi, const float* __restrict__ bh,
    const f16* __restrict__ w1h, const float* __restrict__ b1,
    const f16* __restrict__ w2h, const float* __restrict__ b2,
    const float* __restrict__ gf, const float* __restrict__ bf,
    const float* __restrict__ gs, const float* __restrict__ bs,
    const float* __restrict__ M,
    float* __restrict__ out, f16* __restrict__ qkh) {
  const int r0 = blockIdx.x * 2, r1 = r0 + 1;   // row pair, same batch
  const int t = threadIdx.x;
  __shared__ float urs[2][256], xs[2][256], hs[2][256], ffs[2][256], hid[2][512];
  __shared__ float red[4][4];   // [stat: s1r0,s2r0,s1r1,s2r1][wave]
  const int wave = t >> 6, lane = t & 63;
  const float hv0 = slots[(size_t)r0 * D_ + t];
  const float hv1 = slots[(size_t)r1 * D_ + t];
  const float as0 = asum[r0], as1 = asum[r1];
  urs[0][t] = ur[(size_t)r0 * D_ + t];
  urs[1][t] = ur[(size_t)r1 * D_ + t];
  ur[(size_t)r0 * D_ + t] = 0.f;
  ur[(size_t)r1 * D_ + t] = 0.f;
  hs[0][t] = hv0; hs[1][t] = hv1;
  __syncthreads();
  if (t == 0) { asum[r0] = 0.f; asum[r1] = 0.f; }
  // updates = (u_raw @ Wv)/asum — one fp32 weight load serves both rows
  {
    float u0a = 0.f, u0b = 0.f, u1a = 0.f, u1b = 0.f;
    #pragma unroll 8
    for (int e = 0; e < D_; e += 2) {
      float wA = Wv[(size_t)(e)     * D_ + t];
      float wB = Wv[(size_t)(e + 1) * D_ + t];
      u0a = fmaf(urs[0][e], wA, u0a); u0b = fmaf(urs[0][e + 1], wB, u0b);
      u1a = fmaf(urs[1][e], wA, u1a); u1b = fmaf(urs[1][e + 1], wB, u1b);
    }
    xs[0][t] = (u0a + u0b) / as0;
    xs[1][t] = (u1a + u1b) / as1;
  }
  __syncthreads();
  // GRU gates, f16 weights, both rows per load
  float g0i0 = bi[t], g0i1 = bi[D_ + t], g0i2 = bi[2 * D_ + t];
  float g1i0 = g0i0,  g1i1 = g0i1,       g1i2 = g0i2;
  float g0h0 = bh[t], g0h1 = bh[D_ + t], g0h2 = bh[2 * D_ + t];
  float g1h0 = g0h0,  g1h1 = g0h1,       g1h2 = g0h2;
  #pragma unroll 4
  for (int d = 0; d < D_; ++d) {
    const f16* wid = wiTh + d * 768;
    const f16* whd = whTh + d * 768;
    float wA = (float)wid[t], wB = (float)wid[D_ + t], wC = (float)wid[2 * D_ + t];
    float vA = (float)whd[t], vB = (float)whd[D_ + t], vC = (float)whd[2 * D_ + t];
    float x0 = xs[0][d], x1 = xs[1][d], h0 = hs[0][d], h1 = hs[1][d];
    g0i0 = fmaf(x0, wA, g0i0); g0i1 = fmaf(x0, wB, g0i1); g0i2 = fmaf(x0, wC, g0i2);
    g1i0 = fmaf(x1, wA, g1i0); g1i1 = fmaf(x1, wB, g1i1); g1i2 = fmaf(x1, wC, g1i2);
    g0h0 = fmaf(h0, vA, g0h0); g0h1 = fmaf(h0, vB, g0h1); g0h2 = fmaf(h0, vC, g0h2);
    g1h0 = fmaf(h1, vA, g1h0); g1h1 = fmaf(h1, vB, g1h1); g1h2 = fmaf(h1, vC, g1h2);
  }
  float rr0 = 1.f / (1.f + __expf(-(g0i0 + g0h0)));
  float zz0 = 1.f / (1.f + __expf(-(g0i1 + g0h1)));
  float nn0 = tanhf(g0i2 + rr0 * g0h2);
  float hnew0 = (1.f - zz0) * nn0 + zz0 * hv0;
  float rr1 = 1.f / (1.f + __expf(-(g1i0 + g1h0)));
  float zz1 = 1.f / (1.f + __expf(-(g1i1 + g1h1)));
  float nn1 = tanhf(g1i2 + rr1 * g1h2);
  float hnew1 = (1.f - zz1) * nn1 + zz1 * hv1;
  // LN_ff both rows
  {
    float s10 = hnew0, s20 = hnew0 * hnew0, s11 = hnew1, s21 = hnew1 * hnew1;
    #pragma unroll
    for (int m = 32; m >= 1; m >>= 1) {
      s10 += __shfl_xor(s10, m, 64); s20 += __shfl_xor(s20, m, 64);
      s11 += __shfl_xor(s11, m, 64); s21 += __shfl_xor(s21, m, 64);
    }
    if (lane == 0) { red[0][wave] = s10; red[1][wave] = s20; red[2][wave] = s11; red[3][wave] = s21; }
    __syncthreads();
    s10 = red[0][0] + red[0][1] + red[0][2] + red[0][3];
    s20 = red[1][0] + red[1][1] + red[1][2] + red[1][3];
    s11 = red[2][0] + red[2][1] + red[2][2] + red[2][3];
    s21 = red[3][0] + red[3][1] + red[3][2] + red[3][3];
    float mean0 = s10 * (1.f / D_);
    float rstd0 = rsqrtf(s20 * (1.f / D_) - mean0 * mean0 + LN_EPS_);
    float mean1 = s11 * (1.f / D_);
    float rstd1 = rsqrtf(s21 * (1.f / D_) - mean1 * mean1 + LN_EPS_);
    ffs[0][t] = (hnew0 - mean0) * rstd0 * gf[t] + bf[t];
    ffs[1][t] = (hnew1 - mean1) * rstd1 * gf[t] + bf[t];
  }
  __syncthreads();
  // MLP layer 1 (f16 w1), both rows
  {
    float h0a = b1[t], h0b = b1[D_ + t], h1a = h0a, h1b = h0b;
    #pragma unroll 8
    for (int d = 0; d < D_; ++d) {
      float wA = (float)w1h[(size_t)d * HID_ + t];
      float wB = (float)w1h[(size_t)d * HID_ + D_ + t];
      float f0 = ffs[0][d], f1 = ffs[1][d];
      h0a = fmaf(f0, wA, h0a); h0b = fmaf(f0, wB, h0b);
      h1a = fmaf(f1, wA, h1a); h1b = fmaf(f1, wB, h1b);
    }
    hid[0][t] = fmaxf(h0a, 0.f); hid[0][D_ + t] = fmaxf(h0b, 0.f);
    hid[1][t] = fmaxf(h1a, 0.f); hid[1][D_ + t] = fmaxf(h1b, 0.f);
  }
  __syncthreads();
  // MLP layer 2 (f16 w2), both rows
  float o0, o1;
  {
    float oa0 = b2[t], ob0 = 0.f, oa1 = b2[t], ob1 = 0.f;
    #pragma unroll 8
    for (int d = 0; d < HID_; d += 2) {
      float wA = (float)w2h[(size_t)(d)     * D_ + t];
      float wB = (float)w2h[(size_t)(d + 1) * D_ + t];
      oa0 = fmaf(hid[0][d], wA, oa0); ob0 = fmaf(hid[0][d + 1], wB, ob0);
      oa1 = fmaf(hid[1][d], wA, oa1); ob1 = fmaf(hid[1][d + 1], wB, ob1);
    }
    o0 = oa0 + ob0 + hnew0;
    o1 = oa1 + ob1 + hnew1;
  }
  out[(size_t)r0 * D_ + t] = o0;
  out[(size_t)r1 * D_ + t] = o1;
  // next-iteration qkh = f16( LN_s(new slots) @ M ), both rows
  {
    float s10 = o0, s20 = o0 * o0, s11 = o1, s21 = o1 * o1;
    #pragma unroll
    for (int m = 32; m >= 1; m >>= 1) {
      s10 += __shfl_xor(s10, m, 64); s20 += __shfl_xor(s20, m, 64);
      s11 += __shfl_xor(s11, m, 64); s21 += __shfl_xor(s21, m, 64);
    }
    __syncthreads();
    if (lane == 0) { red[0][wave] = s10; red[1][wave] = s20; red[2][wave] = s11; red[3][wave] = s21; }
    __syncthreads();
    s10 = red[0][0] + red[0][1] + red[0][2] + red[0][3];
    s20 = red[1][0] + red[1][1] + red[1][2] + red[1][3];
    s11 = red[2][0] + red[2][1] + red[2][2] + red[2][3];
    s21 = red[3][0] + red[3][1] + red[3][2] + red[3][3];
    float mean0 = s10 * (1.f / D_);
    float rstd0 = rsqrtf(s20 * (1.f / D_) - mean0 * mean0 + LN_EPS_);
    float mean1 = s11 * (1.f / D_);
    float rstd1 = rsqrtf(s21 * (1.f / D_) - mean1 * mean1 + LN_EPS_);
    ffs[0][t] = (o0 - mean0) * rstd0 * gs[t] + bs[t];
    ffs[1][t] = (o1 - mean1) * rstd1 * gs[t] + bs[t];
  }
  __syncthreads();
  {
    float a00 = 0.f, a01 = 0.f, a10 = 0.f, a11 = 0.f;
    #pragma unroll 8
    for (int d = 0; d < D_; d += 2) {
      float wA = M[(d)     * D_ + t];
      float wB = M[(d + 1) * D_ + t];
      a00 = fmaf(ffs[0][d], wA, a00); a01 = fmaf(ffs[0][d + 1], wB, a01);
      a10 = fmaf(ffs[1][d], wA, a10); a11 = fmaf(ffs[1][d + 1], wB, a11);
    }
    qkh[((size_t)(r0 >> 3) * 16 + (r0 & 7)) * D_ + t] = (f16)(a00 + a01);
    qkh[((size_t)(r1 >> 3) * 16 + (r1 & 7)) * D_ + t] = (f16)(a10 + a11);
  }
}

extern "C" void kernel_launch(void* const* d_in, const int* in_sizes, int n_in,
                              void* d_out, int out_size, void* d_ws, size_t ws_size,
                              hipStream_t stream) {
  (void)in_sizes; (void)n_in; (void)out_size; (void)ws_size;
  const float* inputs = (const float*)d_in[0];
  const float* noise  = (const float*)d_in[1];
  const float* mu     = (const float*)d_in[2];
  const float* ls     = (const float*)d_in[3];
  const float* Wq     = (const float*)d_in[4];
  const float* Wk     = (const float*)d_in[5];
  const float* Wv     = (const float*)d_in[6];
  const float* gwi    = (const float*)d_in[7];
  const float* gwh    = (const float*)d_in[8];
  const float* gbi    = (const float*)d_in[9];
  const float* gbh    = (const float*)d_in[10];
  const float* w1     = (const float*)d_in[11];
  const float* b1     = (const float*)d_in[12];
  const float* w2     = (const float*)d_in[13];
  const float* b2     = (const float*)d_in[14];
  const float* gin    = (const float*)d_in[15];
  const float* bin    = (const float*)d_in[16];
  const float* gs     = (const float*)d_in[17];
  const float* bs     = (const float*)d_in[18];
  const float* gff    = (const float*)d_in[19];
  const float* bff    = (const float*)d_in[20];

  // workspace layout
  const size_t KV = (size_t)B_ * N_ * D_;
  f16*   xh    = (f16*)d_ws;                       // 134 MB
  float* slots = (float*)(xh + KV);                // 131072 f32
  f16*   qkh   = (f16*)(slots + 131072);           // 262144 f16
  float* asum  = (float*)(qkh + 262144);           // 512
  float* ur    = asum + 512;                       // 131072
  float* WkX   = ur + 131072;                      // 65536
  float* M     = WkX + 65536;                      // 65536
  f16*   wiTh  = (f16*)(M + 65536);                // 196608 f16
  f16*   whTh  = wiTh + 196608;
  f16*   w1h   = whTh + 196608;                    // 131072 f16
  f16*   w2h   = w1h + 131072;                     // 131072 f16

  k_setup<<<68096, 256, 0, stream>>>(inputs, gin, bin, xh, Wk, WkX,
                                     gwi, gwh, wiTh, whTh,
                                     noise, mu, ls, slots, w1, w2, w1h, w2h);
  k_m<<<256, 256, 0, stream>>>(Wq, WkX, M);
  k_qk<<<512, 256, 0, stream>>>(slots, gs, bs, M, qkh, ur, asum);
  for (int it = 0; it < 4; ++it) {
    k_attn_upd<<<dim3(N_ / TOK_, B_), 256, 0, stream>>>(xh, qkh, ur, asum);
    float* outp = (it == 3) ? (float*)d_out : slots;
    k_gru_mlp<<<256, 256, 0, stream>>>(ur, asum, slots, Wv, wiTh, whTh, gbi, gbh,
                                       w1h, b1, w2h, b2, gff, bff, gs, bs, M,
                                       outp, qkh);
  }
}

// Round 14
// 838.433 us; speedup vs baseline: 1.5268x; 1.5268x over previous
//
#include <hip/hip_runtime.h>
#include <cstdint>

#define B_ 64
#define N_ 4096
#define D_ 256
#define NS_ 8
#define HID_ 512
#define TOK_ 128
#define EPS_ 1e-8f
#define SCALE_ 0.0625f
#define LN_EPS_ 1e-5f

typedef _Float16 f16;
typedef __attribute__((ext_vector_type(4))) _Float16 f16x4;
typedef __attribute__((ext_vector_type(8))) _Float16 f16x8;
typedef __attribute__((ext_vector_type(4))) float f32x4;

#define MFMA16(a, b, c) __builtin_amdgcn_mfma_f32_16x16x32_f16(a, b, c, 0, 0, 0)

// ---------------- merged setup: xh LN-cast | WkX | GRU-wT cast | slots | w1/w2 cast ----
__global__ __launch_bounds__(256) void k_setup(
    const float* __restrict__ in, const float* __restrict__ gin,
    const float* __restrict__ bin, f16* __restrict__ xh,
    const float* __restrict__ Wk, float* __restrict__ WkX,
    const float* __restrict__ wi, const float* __restrict__ wh,
    f16* __restrict__ wiTh, f16* __restrict__ whTh,
    const float* __restrict__ noise, const float* __restrict__ mu,
    const float* __restrict__ ls, float* __restrict__ slots,
    const float* __restrict__ w1, const float* __restrict__ w2,
    f16* __restrict__ w1h, f16* __restrict__ w2h) {
  const int blk = blockIdx.x;
  const int t = threadIdx.x;
  if (blk < 65536) {
    const int wave = t >> 6, lane = t & 63;
    const size_t row = (size_t)blk * 4 + wave;
    const float* r = in + row * D_;
    float4 a = *(const float4*)(r + lane * 4);
    float s1 = a.x + a.y + a.z + a.w;
    float s2 = a.x * a.x + a.y * a.y + a.z * a.z + a.w * a.w;
    #pragma unroll
    for (int m = 32; m >= 1; m >>= 1) { s1 += __shfl_xor(s1, m, 64); s2 += __shfl_xor(s2, m, 64); }
    const float mean = s1 * (1.f / D_);
    const float rstd = rsqrtf(s2 * (1.f / D_) - mean * mean + LN_EPS_);
    float4 gg = *(const float4*)(gin + lane * 4);
    float4 bv = *(const float4*)(bin + lane * 4);
    f16x4 o;
    o[0] = (f16)((a.x - mean) * rstd * gg.x + bv.x);
    o[1] = (f16)((a.y - mean) * rstd * gg.y + bv.y);
    o[2] = (f16)((a.z - mean) * rstd * gg.z + bv.z);
    o[3] = (f16)((a.w - mean) * rstd * gg.w + bv.w);
    *(f16x4*)(xh + row * D_ + lane * 4) = o;
  } else if (blk < 65792) {
    const int e = blk - 65536;
    WkX[t * 256 + e] = Wk[e * 256 + t];
  } else if (blk < 66560) {
    const int idx = (blk - 65792) * 256 + t;
    const int o = idx >> 8, d = idx & 255;
    wiTh[d * 768 + o] = (f16)wi[idx];
    whTh[d * 768 + o] = (f16)wh[idx];
  } else if (blk < 67072) {
    const int idx = (blk - 66560) * 256 + t;
    const int d = idx & 255;
    slots[idx] = mu[d] + __expf(ls[d]) * noise[idx];
  } else if (blk < 67584) {
    const int idx = (blk - 67072) * 256 + t;
    w1h[idx] = (f16)w1[idx];
  } else {
    const int idx = (blk - 67584) * 256 + t;
    w2h[idx] = (f16)w2[idx];
  }
}

// ---------------- M[c][e] = SCALE * sum_d Wq[c][d] * WkX[d][e] ----------------
__global__ __launch_bounds__(256) void k_m(const float* __restrict__ Wq,
                                           const float* __restrict__ WkX,
                                           float* __restrict__ M) {
  __shared__ float wq[256];
  const int c = blockIdx.x, e = threadIdx.x;
  wq[e] = Wq[c * 256 + e];
  __syncthreads();
  float a0 = 0.f, a1 = 0.f, a2 = 0.f, a3 = 0.f;
  #pragma unroll 8
  for (int d = 0; d < 256; d += 4) {
    a0 = fmaf(wq[d],     WkX[(d)     * 256 + e], a0);
    a1 = fmaf(wq[d + 1], WkX[(d + 1) * 256 + e], a1);
    a2 = fmaf(wq[d + 2], WkX[(d + 2) * 256 + e], a2);
    a3 = fmaf(wq[d + 3], WkX[(d + 3) * 256 + e], a3);
  }
  M[c * 256 + e] = (a0 + a1 + a2 + a3) * SCALE_;
}

// ---------------- qkh = f16( LN(slots) @ M ) + zero ur/asum (once) ----------------
__global__ __launch_bounds__(256) void k_qk(const float* __restrict__ slots,
    const float* __restrict__ g, const float* __restrict__ b,
    const float* __restrict__ M, f16* __restrict__ qkh,
    float* __restrict__ ur, float* __restrict__ asum) {
  const int row = blockIdx.x;
  const int t = threadIdx.x;
  ur[(size_t)row * D_ + t] = 0.f;
  if (t == 0) asum[row] = 0.f;
  __shared__ float sl[256];
  __shared__ float red1[4], red2[4];
  float val = slots[(size_t)row * D_ + t];
  float s1 = val, s2 = val * val;
  #pragma unroll
  for (int m = 32; m >= 1; m >>= 1) { s1 += __shfl_xor(s1, m, 64); s2 += __shfl_xor(s2, m, 64); }
  int wave = t >> 6, lane = t & 63;
  if (lane == 0) { red1[wave] = s1; red2[wave] = s2; }
  __syncthreads();
  s1 = red1[0] + red1[1] + red1[2] + red1[3];
  s2 = red2[0] + red2[1] + red2[2] + red2[3];
  float mean = s1 * (1.f / D_);
  float rstd = rsqrtf(s2 * (1.f / D_) - mean * mean + LN_EPS_);
  sl[t] = (val - mean) * rstd * g[t] + b[t];
  __syncthreads();
  float a0 = 0.f, a1 = 0.f, a2 = 0.f, a3 = 0.f;
  #pragma unroll 8
  for (int d = 0; d < D_; d += 4) {
    a0 = fmaf(sl[d],     M[(d)     * D_ + t], a0);
    a1 = fmaf(sl[d + 1], M[(d + 1) * D_ + t], a1);
    a2 = fmaf(sl[d + 2], M[(d + 2) * D_ + t], a2);
    a3 = fmaf(sl[d + 3], M[(d + 3) * D_ + t], a3);
  }
  qkh[((size_t)(row >> 3) * 16 + (row & 7)) * D_ + t] = (f16)(a0 + a1 + a2 + a3);
}

// ---------------- MFMA attention (round-12 config: TOK_=128) ----------------
__global__ __launch_bounds__(256) void k_attn_upd(
    const f16* __restrict__ xh, const f16* __restrict__ qkh,
    float* __restrict__ ur, float* __restrict__ asum) {
  __shared__ __align__(16) f16 xt[TOK_ * 256];   // 64 KB, chunk-swizzled
  __shared__ __align__(16) f16 qs[16 * 256];     // 8 KB (rows 8-15 pad)
  __shared__ float wv_s[TOK_ * 12];              // 6 KB
  const int b = blockIdx.y;
  const int jt = blockIdx.x * TOK_;
  const int tid = threadIdx.x;
  const int wave = tid >> 6, lane = tid & 63;

  // stage qs
  {
    const int r = tid >> 4, c0 = (tid & 15) * 2;
    const f16* src = qkh + ((size_t)b * 16 + r) * D_;
    *(f16x8*)&qs[r * 256 + ((c0)     ^ (r & 7)) * 8] = *(const f16x8*)(src + c0 * 8);
    *(f16x8*)&qs[r * 256 + ((c0 + 1) ^ (r & 7)) * 8] = *(const f16x8*)(src + c0 * 8 + 8);
  }
  // stage xt: 16 rounds x 4KB, coalesced loads, swizzled ds_write
  {
    const f16* src = xh + ((size_t)b * N_ + jt) * D_;
    f16x8 v[16];
    #pragma unroll
    for (int i = 0; i < 16; ++i) {
      const int r = i * 8 + (tid >> 5), c = tid & 31;
      v[i] = *(const f16x8*)(src + r * 256 + c * 8);
    }
    #pragma unroll
    for (int i = 0; i < 16; ++i) {
      const int r = i * 8 + (tid >> 5), c = tid & 31;
      *(f16x8*)&xt[r * 256 + (c ^ (r & 7)) * 8] = v[i];
    }
  }
  __syncthreads();

  // phase A: MFMA dots; A-frags (qk) loaded once
  const int kg = lane >> 4;
  f16x8 afr[8];
  {
    const int arow = lane & 15;
    #pragma unroll
    for (int kk = 0; kk < 8; ++kk)
      afr[kk] = *(const f16x8*)&qs[arow * 256 + ((kk * 4 + kg) ^ (arow & 7)) * 8];
  }
  float tsum0 = 0.f, tsum1 = 0.f, tsum2 = 0.f, tsum3 = 0.f;
  #pragma unroll
  for (int t2 = 0; t2 < 2; ++t2) {
    const int nt = wave * 2 + t2;
    const int tok = nt * 16 + (lane & 15);
    f32x4 acc = {0.f, 0.f, 0.f, 0.f};
    #pragma unroll
    for (int kk = 0; kk < 8; ++kk) {
      f16x8 bf = *(const f16x8*)&xt[tok * 256 + ((kk * 4 + kg) ^ (tok & 7)) * 8];
      acc = MFMA16(afr[kk], bf, acc);
    }
    float o0 = __shfl_xor(acc[0], 16, 64);
    float o1 = __shfl_xor(acc[1], 16, 64);
    float o2 = __shfl_xor(acc[2], 16, 64);
    float o3 = __shfl_xor(acc[3], 16, 64);
    if (lane < 32) {
      float m = fmaxf(fmaxf(fmaxf(acc[0], acc[1]), fmaxf(acc[2], acc[3])),
                      fmaxf(fmaxf(o0, o1), fmaxf(o2, o3)));
      float e0 = __expf(acc[0] - m), e1 = __expf(acc[1] - m);
      float e2 = __expf(acc[2] - m), e3 = __expf(acc[3] - m);
      float sm = e0 + e1 + e2 + e3;
      float so = __shfl_xor(sm, 16, 64);
      float inv = 1.f / (sm + so);
      float4 wv;
      wv.x = e0 * inv + EPS_; wv.y = e1 * inv + EPS_;
      wv.z = e2 * inv + EPS_; wv.w = e3 * inv + EPS_;
      *(float4*)&wv_s[tok * 12 + (lane >> 4) * 4] = wv;
      float r0 = wv.x, r1 = wv.y, r2 = wv.z, r3 = wv.w;
      #pragma unroll
      for (int mm = 1; mm <= 8; mm <<= 1) {
        r0 += __shfl_xor(r0, mm, 64); r1 += __shfl_xor(r1, mm, 64);
        r2 += __shfl_xor(r2, mm, 64); r3 += __shfl_xor(r3, mm, 64);
      }
      tsum0 += r0; tsum1 += r1; tsum2 += r2; tsum3 += r3;
    }
  }
  if (lane == 0 || lane == 16) {
    const int sb = (lane >> 4) * 4;
    atomicAdd(&asum[b * NS_ + sb + 0], tsum0);
    atomicAdd(&asum[b * NS_ + sb + 1], tsum1);
    atomicAdd(&asum[b * NS_ + sb + 2], tsum2);
    atomicAdd(&asum[b * NS_ + sb + 3], tsum3);
  }
  __syncthreads();

  // phase B: wave -> slots (2w, 2w+1); lane -> d-quad; read LDS tile
  {
    const int i0 = wave * 2;
    const int ch0 = lane >> 1, sub = (lane & 1) * 4;
    float a0[4] = {0.f, 0.f, 0.f, 0.f};
    float a1[4] = {0.f, 0.f, 0.f, 0.f};
    #pragma unroll 4
    for (int j = 0; j < TOK_; ++j) {
      f16x4 v = *(const f16x4*)&xt[j * 256 + (ch0 ^ (j & 7)) * 8 + sub];
      float vx = (float)v[0], vy = (float)v[1], vz = (float)v[2], vw = (float)v[3];
      float w0 = wv_s[j * 12 + i0];
      float w1 = wv_s[j * 12 + i0 + 1];
      a0[0] = fmaf(w0, vx, a0[0]); a0[1] = fmaf(w0, vy, a0[1]);
      a0[2] = fmaf(w0, vz, a0[2]); a0[3] = fmaf(w0, vw, a0[3]);
      a1[0] = fmaf(w1, vx, a1[0]); a1[1] = fmaf(w1, vy, a1[1]);
      a1[2] = fmaf(w1, vz, a1[2]); a1[3] = fmaf(w1, vw, a1[3]);
    }
    float* u0 = ur + ((size_t)b * NS_ + i0) * D_ + lane * 4;
    float* u1 = u0 + D_;
    #pragma unroll
    for (int c = 0; c < 4; ++c) { atomicAdd(u0 + c, a0[c]); atomicAdd(u1 + c, a1[c]); }
  }
}

// ---------------- GRU + LN + MLP + next-qk, TWO rows per block, f16 weights ----------------
__global__ __launch_bounds__(256) void k_gru_mlp(
    float* __restrict__ ur, float* __restrict__ asum,
    const float* __restrict__ slots, const float* __restrict__ Wv,
    const f16* __restrict__ wiTh, const f16* __restrict__ whTh,
    const float* __restrict__ bi, const float* __restrict__ bh,
    const f16* __restrict__ w1h, const float* __restrict__ b1,
    const f16* __restrict__ w2h, const float* __restrict__ b2,
    const float* __restrict__ gf, const float* __restrict__ bf,
    const float* __restrict__ gs, const float* __restrict__ bs,
    const float* __restrict__ M,
    float* __restrict__ out, f16* __restrict__ qkh) {
  const int r0 = blockIdx.x * 2, r1 = r0 + 1;
  const int t = threadIdx.x;
  __shared__ float urs[2][256], xs[2][256], hs[2][256], ffs[2][256], hid[2][512];
  __shared__ float red[4][4];
  const int wave = t >> 6, lane = t & 63;
  const float hv0 = slots[(size_t)r0 * D_ + t];
  const float hv1 = slots[(size_t)r1 * D_ + t];
  const float as0 = asum[r0], as1 = asum[r1];
  urs[0][t] = ur[(size_t)r0 * D_ + t];
  urs[1][t] = ur[(size_t)r1 * D_ + t];
  ur[(size_t)r0 * D_ + t] = 0.f;
  ur[(size_t)r1 * D_ + t] = 0.f;
  hs[0][t] = hv0; hs[1][t] = hv1;
  __syncthreads();
  if (t == 0) { asum[r0] = 0.f; asum[r1] = 0.f; }
  {
    float u0a = 0.f, u0b = 0.f, u1a = 0.f, u1b = 0.f;
    #pragma unroll 8
    for (int e = 0; e < D_; e += 2) {
      float wA = Wv[(size_t)(e)     * D_ + t];
      float wB = Wv[(size_t)(e + 1) * D_ + t];
      u0a = fmaf(urs[0][e], wA, u0a); u0b = fmaf(urs[0][e + 1], wB, u0b);
      u1a = fmaf(urs[1][e], wA, u1a); u1b = fmaf(urs[1][e + 1], wB, u1b);
    }
    xs[0][t] = (u0a + u0b) / as0;
    xs[1][t] = (u1a + u1b) / as1;
  }
  __syncthreads();
  float g0i0 = bi[t], g0i1 = bi[D_ + t], g0i2 = bi[2 * D_ + t];
  float g1i0 = g0i0,  g1i1 = g0i1,       g1i2 = g0i2;
  float g0h0 = bh[t], g0h1 = bh[D_ + t], g0h2 = bh[2 * D_ + t];
  float g1h0 = g0h0,  g1h1 = g0h1,       g1h2 = g0h2;
  #pragma unroll 4
  for (int d = 0; d < D_; ++d) {
    const f16* wid = wiTh + d * 768;
    const f16* whd = whTh + d * 768;
    float wA = (float)wid[t], wB = (float)wid[D_ + t], wC = (float)wid[2 * D_ + t];
    float vA = (float)whd[t], vB = (float)whd[D_ + t], vC = (float)whd[2 * D_ + t];
    float x0 = xs[0][d], x1 = xs[1][d], h0 = hs[0][d], h1 = hs[1][d];
    g0i0 = fmaf(x0, wA, g0i0); g0i1 = fmaf(x0, wB, g0i1); g0i2 = fmaf(x0, wC, g0i2);
    g1i0 = fmaf(x1, wA, g1i0); g1i1 = fmaf(x1, wB, g1i1); g1i2 = fmaf(x1, wC, g1i2);
    g0h0 = fmaf(h0, vA, g0h0); g0h1 = fmaf(h0, vB, g0h1); g0h2 = fmaf(h0, vC, g0h2);
    g1h0 = fmaf(h1, vA, g1h0); g1h1 = fmaf(h1, vB, g1h1); g1h2 = fmaf(h1, vC, g1h2);
  }
  float rr0 = 1.f / (1.f + __expf(-(g0i0 + g0h0)));
  float zz0 = 1.f / (1.f + __expf(-(g0i1 + g0h1)));
  float nn0 = tanhf(g0i2 + rr0 * g0h2);
  float hnew0 = (1.f - zz0) * nn0 + zz0 * hv0;
  float rr1 = 1.f / (1.f + __expf(-(g1i0 + g1h0)));
  float zz1 = 1.f / (1.f + __expf(-(g1i1 + g1h1)));
  float nn1 = tanhf(g1i2 + rr1 * g1h2);
  float hnew1 = (1.f - zz1) * nn1 + zz1 * hv1;
  {
    float s10 = hnew0, s20 = hnew0 * hnew0, s11 = hnew1, s21 = hnew1 * hnew1;
    #pragma unroll
    for (int m = 32; m >= 1; m >>= 1) {
      s10 += __shfl_xor(s10, m, 64); s20 += __shfl_xor(s20, m, 64);
      s11 += __shfl_xor(s11, m, 64); s21 += __shfl_xor(s21, m, 64);
    }
    if (lane == 0) { red[0][wave] = s10; red[1][wave] = s20; red[2][wave] = s11; red[3][wave] = s21; }
    __syncthreads();
    s10 = red[0][0] + red[0][1] + red[0][2] + red[0][3];
    s20 = red[1][0] + red[1][1] + red[1][2] + red[1][3];
    s11 = red[2][0] + red[2][1] + red[2][2] + red[2][3];
    s21 = red[3][0] + red[3][1] + red[3][2] + red[3][3];
    float mean0 = s10 * (1.f / D_);
    float rstd0 = rsqrtf(s20 * (1.f / D_) - mean0 * mean0 + LN_EPS_);
    float mean1 = s11 * (1.f / D_);
    float rstd1 = rsqrtf(s21 * (1.f / D_) - mean1 * mean1 + LN_EPS_);
    ffs[0][t] = (hnew0 - mean0) * rstd0 * gf[t] + bf[t];
    ffs[1][t] = (hnew1 - mean1) * rstd1 * gf[t] + bf[t];
  }
  __syncthreads();
  {
    float h0a = b1[t], h0b = b1[D_ + t], h1a = h0a, h1b = h0b;
    #pragma unroll 8
    for (int d = 0; d < D_; ++d) {
      float wA = (float)w1h[(size_t)d * HID_ + t];
      float wB = (float)w1h[(size_t)d * HID_ + D_ + t];
      float f0 = ffs[0][d], f1 = ffs[1][d];
      h0a = fmaf(f0, wA, h0a); h0b = fmaf(f0, wB, h0b);
      h1a = fmaf(f1, wA, h1a); h1b = fmaf(f1, wB, h1b);
    }
    hid[0][t] = fmaxf(h0a, 0.f); hid[0][D_ + t] = fmaxf(h0b, 0.f);
    hid[1][t] = fmaxf(h1a, 0.f); hid[1][D_ + t] = fmaxf(h1b, 0.f);
  }
  __syncthreads();
  float o0, o1;
  {
    float oa0 = b2[t], ob0 = 0.f, oa1 = b2[t], ob1 = 0.f;
    #pragma unroll 8
    for (int d = 0; d < HID_; d += 2) {
      float wA = (float)w2h[(size_t)(d)     * D_ + t];
      float wB = (float)w2h[(size_t)(d + 1) * D_ + t];
      oa0 = fmaf(hid[0][d], wA, oa0); ob0 = fmaf(hid[0][d + 1], wB, ob0);
      oa1 = fmaf(hid[1][d], wA, oa1); ob1 = fmaf(hid[1][d + 1], wB, ob1);
    }
    o0 = oa0 + ob0 + hnew0;
    o1 = oa1 + ob1 + hnew1;
  }
  out[(size_t)r0 * D_ + t] = o0;
  out[(size_t)r1 * D_ + t] = o1;
  {
    float s10 = o0, s20 = o0 * o0, s11 = o1, s21 = o1 * o1;
    #pragma unroll
    for (int m = 32; m >= 1; m >>= 1) {
      s10 += __shfl_xor(s10, m, 64); s20 += __shfl_xor(s20, m, 64);
      s11 += __shfl_xor(s11, m, 64); s21 += __shfl_xor(s21, m, 64);
    }
    __syncthreads();
    if (lane == 0) { red[0][wave] = s10; red[1][wave] = s20; red[2][wave] = s11; red[3][wave] = s21; }
    __syncthreads();
    s10 = red[0][0] + red[0][1] + red[0][2] + red[0][3];
    s20 = red[1][0] + red[1][1] + red[1][2] + red[1][3];
    s11 = red[2][0] + red[2][1] + red[2][2] + red[2][3];
    s21 = red[3][0] + red[3][1] + red[3][2] + red[3][3];
    float mean0 = s10 * (1.f / D_);
    float rstd0 = rsqrtf(s20 * (1.f / D_) - mean0 * mean0 + LN_EPS_);
    float mean1 = s11 * (1.f / D_);
    float rstd1 = rsqrtf(s21 * (1.f / D_) - mean1 * mean1 + LN_EPS_);
    ffs[0][t] = (o0 - mean0) * rstd0 * gs[t] + bs[t];
    ffs[1][t] = (o1 - mean1) * rstd1 * gs[t] + bs[t];
  }
  __syncthreads();
  {
    float a00 = 0.f, a01 = 0.f, a10 = 0.f, a11 = 0.f;
    #pragma unroll 8
    for (int d = 0; d < D_; d += 2) {
      float wA = M[(d)     * D_ + t];
      float wB = M[(d + 1) * D_ + t];
      a00 = fmaf(ffs[0][d], wA, a00); a01 = fmaf(ffs[0][d + 1], wB, a01);
      a10 = fmaf(ffs[1][d], wA, a10); a11 = fmaf(ffs[1][d + 1], wB, a11);
    }
    qkh[((size_t)(r0 >> 3) * 16 + (r0 & 7)) * D_ + t] = (f16)(a00 + a01);
    qkh[((size_t)(r1 >> 3) * 16 + (r1 & 7)) * D_ + t] = (f16)(a10 + a11);
  }
}

extern "C" void kernel_launch(void* const* d_in, const int* in_sizes, int n_in,
                              void* d_out, int out_size, void* d_ws, size_t ws_size,
                              hipStream_t stream) {
  (void)in_sizes; (void)n_in; (void)out_size; (void)ws_size;
  const float* inputs = (const float*)d_in[0];
  const float* noise  = (const float*)d_in[1];
  const float* mu     = (const float*)d_in[2];
  const float* ls     = (const float*)d_in[3];
  const float* Wq     = (const float*)d_in[4];
  const float* Wk     = (const float*)d_in[5];
  const float* Wv     = (const float*)d_in[6];
  const float* gwi    = (const float*)d_in[7];
  const float* gwh    = (const float*)d_in[8];
  const float* gbi    = (const float*)d_in[9];
  const float* gbh    = (const float*)d_in[10];
  const float* w1     = (const float*)d_in[11];
  const float* b1     = (const float*)d_in[12];
  const float* w2     = (const float*)d_in[13];
  const float* b2     = (const float*)d_in[14];
  const float* gin    = (const float*)d_in[15];
  const float* bin    = (const float*)d_in[16];
  const float* gs     = (const float*)d_in[17];
  const float* bs     = (const float*)d_in[18];
  const float* gff    = (const float*)d_in[19];
  const float* bff    = (const float*)d_in[20];

  // workspace layout
  const size_t KV = (size_t)B_ * N_ * D_;
  f16*   xh    = (f16*)d_ws;                       // 134 MB
  float* slots = (float*)(xh + KV);
  f16*   qkh   = (f16*)(slots + 131072);
  float* asum  = (float*)(qkh + 262144);
  float* ur    = asum + 512;
  float* WkX   = ur + 131072;
  float* M     = WkX + 65536;
  f16*   wiTh  = (f16*)(M + 65536);
  f16*   whTh  = wiTh + 196608;
  f16*   w1h   = whTh + 196608;
  f16*   w2h   = w1h + 131072;

  k_setup<<<68096, 256, 0, stream>>>(inputs, gin, bin, xh, Wk, WkX,
                                     gwi, gwh, wiTh, whTh,
                                     noise, mu, ls, slots, w1, w2, w1h, w2h);
  k_m<<<256, 256, 0, stream>>>(Wq, WkX, M);
  k_qk<<<512, 256, 0, stream>>>(slots, gs, bs, M, qkh, ur, asum);
  for (int it = 0; it < 4; ++it) {
    k_attn_upd<<<dim3(N_ / TOK_, B_), 256, 0, stream>>>(xh, qkh, ur, asum);
    float* outp = (it == 3) ? (float*)d_out : slots;
    k_gru_mlp<<<256, 256, 0, stream>>>(ur, asum, slots, Wv, wiTh, whTh, gbi, gbh,
                                       w1h, b1, w2h, b2, gff, bff, gs, bs, M,
                                       outp, qkh);
  }
}